// Round 5
// baseline (19.570 us; speedup 1.0000x reference)
//
#include <hip/hip_runtime.h>

#define H 48
#define W 64
#define C 256
#define NK 21                  // 21 displacements per axis
#define HW (H * W)             // 3072
#define NG 11                  // oy-pair groups per y (oy = 2g, 2g+1; g=10 -> oy=20 only)
#define HSTRIDE 272            // bytes per x-row of a 128-channel half (256B data + 16B pad)
#define HTENSOR (64 * HSTRIDE) // 17408 B per staged half row-slice

typedef __attribute__((ext_vector_type(8))) short bf16x8;
typedef __attribute__((ext_vector_type(4))) float f32x4;

// pack two fp32 -> two bf16 (RNE) in one u32: lo = bf(a), hi = bf(b)
__device__ __forceinline__ unsigned pack2bf(float a, float b) {
  unsigned ua = __builtin_bit_cast(unsigned, a);
  unsigned ub = __builtin_bit_cast(unsigned, b);
  ua = (ua + 0x7FFFu + ((ua >> 16) & 1u)) >> 16;
  ub = (ub + 0x7FFFu + ((ub >> 16) & 1u)) & 0xFFFF0000u;
  return ua | ub;
}

// Stage half kh (128 channels) of row-slice src[c][x] into LDS as bf16 [x][c-128kh],
// row stride HSTRIDE. Per thread: 4 iters x (8 coalesced 256B loads + pack + 1 b128 write).
// Bank check: write addr = lane*272 + oct*16 -> per-16-lane phase 2 lanes/bank = free.
__device__ __forceinline__ void stage_half(const float* __restrict__ src, char* lds,
                                           int kh, int tid) {
  const int lane = tid & 63, wave = tid >> 6;
  const float* col = src + (size_t)kh * 128 * HW + lane;  // x = lane
#pragma unroll
  for (int i = 0; i < 4; ++i) {
    const int oct = i * 4 + wave;  // c-octet 0..15 within the half
    const float* p = col + (size_t)oct * 8 * HW;
    float v0 = p[0], v1 = p[HW], v2 = p[2 * HW], v3 = p[3 * HW];
    float v4 = p[4 * HW], v5 = p[5 * HW], v6 = p[6 * HW], v7 = p[7 * HW];
    uint4 w;
    w.x = pack2bf(v0, v1);
    w.y = pack2bf(v2, v3);
    w.z = pack2bf(v4, v5);
    w.w = pack2bf(v6, v7);
    *reinterpret_cast<uint4*>(lds + lane * HSTRIDE + oct * 16) = w;
  }
}

// One block per (y, oy-pair). Stages A = f1 row y ONCE for both jobs (cuts the
// redundant fp32 re-read from 128KB/job to 96KB/job), K-split into two
// 128-channel halves so LDS = 3*17KB = 51KB -> 3 blocks/CU co-resident.
__global__ __launch_bounds__(256, 3) void corr_pair(
    const float* __restrict__ f1, const float* __restrict__ f2, float* __restrict__ out) {
  __shared__ char smem[3 * HTENSOR];  // A | B0 | B1 ; M (64x66 f32) overlays A
  const int b = blockIdx.x;
  const int y = b / NG, g = b % NG;
  const int oy0 = 2 * g, oy1 = 2 * g + 1;
  const bool ex1 = (oy1 < NK);
  const int r0 = y + 2 * oy0 - 20;
  const int r1 = y + 2 * oy1 - 20;
  const bool v0 = (unsigned)r0 < (unsigned)H;
  const bool v1 = ex1 && ((unsigned)r1 < (unsigned)H);
  const int tid = threadIdx.x;
  const int wave = tid >> 6, lane = tid & 63;

  // zero-fill helper for an existing-but-out-of-range oy band
  auto zerofill = [&](int oyi) {
    float* ob = out + (size_t)(oyi * NK) * HW + y * W;
    for (int i = tid; i < NK * W; i += 256) {
      int oxi = i >> 6, x = i & 63;
      ob[(size_t)oxi * HW + x] = 0.f;
    }
  };

  if (!v0 && !v1) {  // nothing to compute
    zerofill(oy0);
    if (ex1) zerofill(oy1);
    return;
  }

  f32x4 acc0[4] = {};
  f32x4 acc1[4] = {};

#pragma unroll
  for (int kh = 0; kh < 2; ++kh) {
    if (kh) __syncthreads();  // previous half's MFMA reads done before overwrite
    stage_half(f1 + (size_t)y * W, smem, kh, tid);
    if (v0) stage_half(f2 + (size_t)r0 * W, smem + HTENSOR, kh, tid);
    if (v1) stage_half(f2 + (size_t)r1 * W, smem + 2 * HTENSOR, kh, tid);
    __syncthreads();

    // 64x64x128 Gram contribution; wave w owns output rows [16w,16w+16)
    const int koff = (lane >> 4) << 4;
    const char* aRow = smem + (wave * 16 + (lane & 15)) * HSTRIDE + koff;
    if (v0) {
      const char* bRow = smem + HTENSOR + (lane & 15) * HSTRIDE + koff;
#pragma unroll
      for (int ks = 0; ks < 4; ++ks) {
        bf16x8 a = *reinterpret_cast<const bf16x8*>(aRow + ks * 64);
#pragma unroll
        for (int tn = 0; tn < 4; ++tn) {
          bf16x8 bb = *reinterpret_cast<const bf16x8*>(bRow + (tn * 16) * HSTRIDE + ks * 64);
          acc0[tn] = __builtin_amdgcn_mfma_f32_16x16x32_bf16(a, bb, acc0[tn], 0, 0, 0);
        }
      }
    }
    if (v1) {
      const char* bRow = smem + 2 * HTENSOR + (lane & 15) * HSTRIDE + koff;
#pragma unroll
      for (int ks = 0; ks < 4; ++ks) {
        bf16x8 a = *reinterpret_cast<const bf16x8*>(aRow + ks * 64);
#pragma unroll
        for (int tn = 0; tn < 4; ++tn) {
          bf16x8 bb = *reinterpret_cast<const bf16x8*>(bRow + (tn * 16) * HSTRIDE + ks * 64);
          acc1[tn] = __builtin_amdgcn_mfma_f32_16x16x32_bf16(a, bb, acc1[tn], 0, 0, 0);
        }
      }
    }
  }
  __syncthreads();  // all MFMA reads of the A region done before overlaying M

  float* M = (float*)smem;  // [64][66] overlays A region (16896 B <= 17408 B)

  // M-write banks: per (tn,j) instr, idx = 264*(lane>>4)+(lane&15) -> 2-way = free.
  // Extraction banks: idx = 67*x + const, stride-3 banks over 64 lanes -> 2-way = free.
  auto emit = [&](const f32x4* acc, int oyi) {
    float* ob = out + (size_t)(oyi * NK) * HW + y * W;
#pragma unroll
    for (int tn = 0; tn < 4; ++tn) {
#pragma unroll
      for (int j = 0; j < 4; ++j) {
        int x1 = (wave << 4) + ((lane >> 4) << 2) + j;  // C/D layout (m89)
        int x2 = (tn << 4) + (lane & 15);
        M[x1 * 66 + x2] = acc[tn][j];
      }
    }
    __syncthreads();
    for (int i = tid; i < NK * W; i += 256) {
      int oxi = i >> 6, x = i & 63;
      int x2 = x + 2 * oxi - 20;
      float v = ((unsigned)x2 < (unsigned)W) ? M[x * 66 + x2] : 0.f;
      ob[(size_t)oxi * HW + x] = v;
    }
  };

  // block-uniform branches -> barriers inside are safe
  if (v0) emit(acc0, oy0); else zerofill(oy0);
  if (ex1) {
    if (v1) {
      __syncthreads();  // job0's extraction reads of M done before overwrite
      emit(acc1, oy1);
    } else {
      zerofill(oy1);
    }
  }
}

extern "C" void kernel_launch(void* const* d_in, const int* in_sizes, int n_in,
                              void* d_out, int out_size, void* d_ws, size_t ws_size,
                              hipStream_t stream) {
  (void)in_sizes; (void)n_in; (void)d_ws; (void)ws_size; (void)out_size;
  const float* f1 = (const float*)d_in[0];
  const float* f2 = (const float*)d_in[1];
  float* out = (float*)d_out;
  corr_pair<<<H * NG, 256, 0, stream>>>(f1, f2, out);
}

// Round 7
// 16.834 us; speedup vs baseline: 1.1626x; 1.1626x over previous
//
#include <hip/hip_runtime.h>
#include <hip/hip_bf16.h>

#define H 48
#define W 64
#define C 256
#define NK 21                  // 21 displacements per axis
#define HW (H * W)             // 3072
#define HSTRIDE 272            // bytes per x-row of a 128-channel half (256B data + 16B pad)
#define HTENSOR (64 * HSTRIDE) // 17408 B per staged half row-slice

typedef __attribute__((ext_vector_type(8))) short bf16x8;
typedef __attribute__((ext_vector_type(4))) float f32x4;

// pack two fp32 -> two bf16 (RNE); lowers to packed cvt (v_cvt_pk_bf16_f32)
__device__ __forceinline__ unsigned pack2bf(float a, float b) {
  __hip_bfloat162 h = __float22bfloat162_rn(make_float2(a, b));
  unsigned u;
  __builtin_memcpy(&u, &h, 4);
  return u;
}

// Stage half kh (128 channels) of row-slice src[c][x] (element src[c*HW+x]) into
// LDS as bf16 [x][c-128*kh], row stride HSTRIDE.
// Per thread: 4 iters x (8 coalesced 256B lane-stride loads + 4 cvt_pk + 1 ds_write_b128).
// Write banks: addr = lane*272 + oct*16 -> per-16-lane phase 2 lanes/bank = free.
__device__ __forceinline__ void stage_half(const float* __restrict__ src, char* lds,
                                           int kh, int tid) {
  const int lane = tid & 63, wave = tid >> 6;
  const float* col = src + (size_t)kh * 128 * HW + lane;  // x = lane
#pragma unroll
  for (int i = 0; i < 4; ++i) {
    const int oct = i * 4 + wave;  // c-octet 0..15 within the half
    const float* p = col + (size_t)oct * 8 * HW;
    float v0 = p[0], v1 = p[HW], v2 = p[2 * HW], v3 = p[3 * HW];
    float v4 = p[4 * HW], v5 = p[5 * HW], v6 = p[6 * HW], v7 = p[7 * HW];
    uint4 w;
    w.x = pack2bf(v0, v1);
    w.y = pack2bf(v2, v3);
    w.z = pack2bf(v4, v5);
    w.w = pack2bf(v6, v7);
    *reinterpret_cast<uint4*>(lds + lane * HSTRIDE + oct * 16) = w;
  }
}

// One block per (y, oyi) job; K processed in two 128-channel halves so LDS =
// 2*17KB = 34.8KB -> 4 blocks/CU (all 1008 blocks co-resident, one generation).
__global__ __launch_bounds__(256, 4) void corr_fused(
    const float* __restrict__ f1, const float* __restrict__ f2, float* __restrict__ out) {
  __shared__ char smem[2 * HTENSOR];  // A-half | B-half ; M (64x66 f32) overlays A
  const int b = blockIdx.x;
  const int y = b / NK, oyi = b % NK;
  const int r = y + 2 * oyi - 20;
  const int tid = threadIdx.x;
  float* outBase = out + (size_t)(oyi * NK) * HW + y * W;  // + oxi*HW + x

  if ((unsigned)r >= (unsigned)H) {  // whole oy-band out of range -> zeros
    for (int i = tid; i < NK * W; i += 256) {
      int oxi = i >> 6, x = i & 63;
      outBase[(size_t)oxi * HW + x] = 0.f;
    }
    return;
  }

  const int wave = tid >> 6, lane = tid & 63;
  f32x4 acc[4] = {};
  const int koff = (lane >> 4) << 4;  // k-byte offset within the 32-k group

#pragma unroll
  for (int kh = 0; kh < 2; ++kh) {
    if (kh) __syncthreads();  // previous half's MFMA reads done before overwrite
    stage_half(f1 + (size_t)y * W, smem, kh, tid);
    stage_half(f2 + (size_t)r * W, smem + HTENSOR, kh, tid);
    __syncthreads();

    // 64x64x128 Gram contribution; wave w owns output rows [16w,16w+16)
    const char* aRow = smem + (wave * 16 + (lane & 15)) * HSTRIDE + koff;
    const char* bRow = smem + HTENSOR + (lane & 15) * HSTRIDE + koff;
#pragma unroll
    for (int ks = 0; ks < 4; ++ks) {
      bf16x8 a = *reinterpret_cast<const bf16x8*>(aRow + ks * 64);
#pragma unroll
      for (int tn = 0; tn < 4; ++tn) {
        bf16x8 bb = *reinterpret_cast<const bf16x8*>(bRow + (tn * 16) * HSTRIDE + ks * 64);
        acc[tn] = __builtin_amdgcn_mfma_f32_16x16x32_bf16(a, bb, acc[tn], 0, 0, 0);
      }
    }
  }
  __syncthreads();  // all MFMA reads of the A region done before overlaying M

  // ---- write M to LDS; C/D layout: col=lane&15, row=(lane>>4)*4+reg (m89)
  float* M = (float*)smem;  // [64][66] overlays A region (16896 B <= 17408 B)
#pragma unroll
  for (int tn = 0; tn < 4; ++tn) {
#pragma unroll
    for (int j = 0; j < 4; ++j) {
      int x1 = (wave << 4) + ((lane >> 4) << 2) + j;
      int x2 = (tn << 4) + (lane & 15);
      M[x1 * 66 + x2] = acc[tn][j];
    }
  }
  __syncthreads();

  // ---- band extraction: out[(oyi*21+oxi), y, x] = M[x][x + 2*oxi - 20]
  for (int i = tid; i < NK * W; i += 256) {
    int oxi = i >> 6, x = i & 63;
    int x2 = x + 2 * oxi - 20;
    float v = ((unsigned)x2 < (unsigned)W) ? M[x * 66 + x2] : 0.f;
    outBase[(size_t)oxi * HW + x] = v;
  }
}

extern "C" void kernel_launch(void* const* d_in, const int* in_sizes, int n_in,
                              void* d_out, int out_size, void* d_ws, size_t ws_size,
                              hipStream_t stream) {
  (void)in_sizes; (void)n_in; (void)d_ws; (void)ws_size; (void)out_size;
  const float* f1 = (const float*)d_in[0];
  const float* f2 = (const float*)d_in[1];
  float* out = (float*)d_out;
  corr_fused<<<H * NK, 256, 0, stream>>>(f1, f2, out);
}